// Round 15
// baseline (33.719 us; speedup 1.0000x reference)
//
#include <hip/hip_runtime.h>
#include <stdint.h>

// IAF inversion via incremental MADE recurrence — R13 skeleton with:
//   * 8-buffer rotation (prefetch distance ~8 steps ~1700+cyc): the
//     discriminating test for "load-at-use stall" vs "structural floor".
//   * x-injection: mu-weights pre-NEGATED in pack; lane (d&63) adds its own
//     xa/xb into the mu partial BEFORE reduction -> reduced sum = x - mu.
//     Removes the per-step xv readlane + VALU<->SALU hazard.
//   * loop split into two 64-step halves: xa/za first, xb/zb second
//     (compile-time selection, no u<64 selects; dl = in-half index).
// 1024 single-wave blocks (1 wave/SIMD), pk-packed f32 math, biases folded
// out of the loop (exact; b2==0 here anyway). DPP reduce to lane63, one
// readlane broadcast of zd per step (proven R13 pattern).

#define Bz  1024
#define Dd  128
#define Hh  512
#define LN2 0.6931471805599453f
#define NRL -1.4426950408889634f   // -1/ln2

typedef float v4f __attribute__((ext_vector_type(4)));
typedef float v2f __attribute__((ext_vector_type(2)));

#define LOQ(q) __builtin_shufflevector(q, q, 0, 1)
#define HIQ(q) __builtin_shufflevector(q, q, 2, 3)

// ---------------- DPP wave-64 sum ----------------
template<int CTRL, int RMASK>
__device__ __forceinline__ float dpp_add(float v) {
    int t = __builtin_amdgcn_update_dpp(0, __float_as_int(v), CTRL, RMASK, 0xf, true);
    return v + __int_as_float(t);
}
__device__ __forceinline__ float wave_sum63(float v) {   // total in lane 63
    v = dpp_add<0x111, 0xf>(v);  // row_shr:1
    v = dpp_add<0x112, 0xf>(v);  // row_shr:2
    v = dpp_add<0x114, 0xf>(v);  // row_shr:4
    v = dpp_add<0x118, 0xf>(v);  // row_shr:8
    v = dpp_add<0x142, 0xa>(v);  // row_bcast:15
    v = dpp_add<0x143, 0xc>(v);  // row_bcast:31
    return v;
}
__device__ __forceinline__ float bcast_lane(float v, int l) {
    return __int_as_float(__builtin_amdgcn_readlane(__float_as_int(v), l));
}
__device__ __forceinline__ float wave_sum_bcast(float v) {
    return bcast_lane(wave_sum63(v), 63);
}

// ---------------- pre-pack masked weights ----------------
// Wp[d*1536 + 0..511]     = W2[d,h]   * (m_hid<=d) * (-1/ln2)    (sigma')
// Wp[d*1536 + 512..1023]  = -W2[D+d,h]* (m_hid<=d)               (NEG mu!)
// Wp[d*1536 + 1024..1535] = W1[h,d]   * (m_hid> d) * exp(-b2[d]) (E_d fold)
__global__ void pack_kernel(const float* __restrict__ W1,
                            const float* __restrict__ W2,
                            const float* __restrict__ b2,
                            float* __restrict__ Wp) {
    int idx = blockIdx.x * blockDim.x + threadIdx.x;
    if (idx >= Dd * Hh) return;
    int d = idx >> 9, h = idx & 511;
    int mh = (h % 127) + 1;
    float* bp = Wp + d * 1536;
    bp[h]        = W2[d * Hh + h] * ((mh <= d) ? NRL : 0.f);
    bp[512 + h]  = -W2[(Dd + d) * Hh + h] * ((mh <= d) ? 1.f : 0.f);
    bp[1024 + h] = W1[h * Dd + d] * ((mh > d) ? __expf(-b2[d]) : 0.f);
}

// ---------------- weight buffer (24 VGPRs each; 8 buffers = 192) ---------
struct WBuf { v4f s0, s1, m0, m1, w0, w1; };

__device__ __forceinline__ void loadbuf(WBuf &b, const float* p) {
    b.s0 = *(const v4f*)(p);          // sigma' (masked, *NRL)
    b.s1 = *(const v4f*)(p + 4);
    b.m0 = *(const v4f*)(p + 512);    // -mu (masked, negated)
    b.m1 = *(const v4f*)(p + 516);
    b.w0 = *(const v4f*)(p + 1024);   // W1 col (masked, *E_d)
    b.w1 = *(const v4f*)(p + 1028);
    __builtin_amdgcn_sched_barrier(0);  // pin issue point
}

// ---------------- one recurrence step (pk math, x-injection) -------------
// dl = step index within current half (0..63); xv = this lane's x' value.
__device__ __forceinline__ void stepD(int dl, int lane,
    v2f (&a2)[4], const WBuf &w, float xv,
    float &zcap, float &ldet63)
{
    const v2f zz = {0.f, 0.f};
    v2f h0 = __builtin_elementwise_max(a2[0], zz);
    v2f h1 = __builtin_elementwise_max(a2[1], zz);
    v2f h2 = __builtin_elementwise_max(a2[2], zz);
    v2f h3 = __builtin_elementwise_max(a2[3], zz);

    v2f psA = zz, psB = zz, pmA = zz, pmB = zz;
    psA = __builtin_elementwise_fma(h0, (v2f)LOQ(w.s0), psA);
    pmA = __builtin_elementwise_fma(h0, (v2f)LOQ(w.m0), pmA);
    psB = __builtin_elementwise_fma(h1, (v2f)HIQ(w.s0), psB);
    pmB = __builtin_elementwise_fma(h1, (v2f)HIQ(w.m0), pmB);
    psA = __builtin_elementwise_fma(h2, (v2f)LOQ(w.s1), psA);
    pmA = __builtin_elementwise_fma(h2, (v2f)LOQ(w.m1), pmA);
    psB = __builtin_elementwise_fma(h3, (v2f)HIQ(w.s1), psB);
    pmB = __builtin_elementwise_fma(h3, (v2f)HIQ(w.m1), pmB);
    v2f psp = psA + psB;             // v_pk_add_f32
    v2f pmp = pmA + pmB;

    float pspart = psp.x + psp.y;
    float pmpart = pmp.x + pmp.y;

    bool sel = (lane == dl);
    pmpart += sel ? xv : 0.f;        // inject x: reduced sum = x - mu

    float sp = wave_sum63(pspart);   // -s/ln2, valid on lane63
    float sm = wave_sum63(pmpart);   // x - mu,  valid on lane63

    float zd63 = sm * __builtin_amdgcn_exp2f(sp);  // valid on lane63
    ldet63 += sp;                                   // lane63 accumulates
    float zd = bcast_lane(zd63, 63);                // ONE broadcast
    if (sel) zcap = zd;

    v2f zd2 = {zd, zd};
    a2[0] = __builtin_elementwise_fma(zd2, (v2f)LOQ(w.w0), a2[0]);
    a2[1] = __builtin_elementwise_fma(zd2, (v2f)HIQ(w.w0), a2[1]);
    a2[2] = __builtin_elementwise_fma(zd2, (v2f)LOQ(w.w1), a2[2]);
    a2[3] = __builtin_elementwise_fma(zd2, (v2f)HIQ(w.w1), a2[3]);
}

__global__ __launch_bounds__(64, 1) void iaf14_kernel(
    const float* __restrict__ x,
    const float* __restrict__ b1,
    const float* __restrict__ b2,
    const float* __restrict__ Wp,
    float* __restrict__ out)
{
    const int lane = (int)threadIdx.x;
    const int row  = (int)blockIdx.x;
    const int h0   = lane * 8;

    // ---- per-row state: preacts (pk pairs), bias-folded x, epilogue E ----
    v2f a2[4];
    {
        v4f t0v = *(const v4f*)(b1 + h0);
        v4f t1v = *(const v4f*)(b1 + h0 + 4);
        a2[0] = LOQ(t0v); a2[1] = HIQ(t0v);
        a2[2] = LOQ(t1v); a2[3] = HIQ(t1v);
    }
    float bsa = b2[lane],       bsb = b2[64 + lane];    // sigma biases
    float bma = b2[128 + lane], bmb = b2[192 + lane];   // mu biases
    float xa  = x[row * Dd + lane]      - bma;          // x' = x - b2_mu
    float xb  = x[row * Dd + 64 + lane] - bmb;
    float Ea  = __builtin_amdgcn_exp2f(bsa * NRL);      // E_d for za lanes
    float Eb  = __builtin_amdgcn_exp2f(bsb * NRL);      // E_d for zb lanes
    float Csum = NRL * wave_sum_bcast(bsa + bsb);       // sum_d b2[d]*NRL

    float za = 0.f, zb = 0.f, ldet = 0.f;               // ldet on lane63

    const float* base = Wp + h0;
    WBuf W0, W1r, W2r, W3, W4, W5, W6, W7;
    loadbuf(W0,  base + 0 * 1536);
    loadbuf(W1r, base + 1 * 1536);
    loadbuf(W2r, base + 2 * 1536);
    loadbuf(W3,  base + 3 * 1536);
    loadbuf(W4,  base + 4 * 1536);
    loadbuf(W5,  base + 5 * 1536);
    loadbuf(W6,  base + 6 * 1536);
    loadbuf(W7,  base + 7 * 1536);

    // ---- first half: steps 0..63, xv=xa, capture za ----
#pragma unroll 1
    for (int t = 0; t < 64; t += 8) {
        stepD(t + 0, lane, a2, W0,  xa, za, ldet); loadbuf(W0,  base + (size_t)(t +  8) * 1536);
        stepD(t + 1, lane, a2, W1r, xa, za, ldet); loadbuf(W1r, base + (size_t)(t +  9) * 1536);
        stepD(t + 2, lane, a2, W2r, xa, za, ldet); loadbuf(W2r, base + (size_t)(t + 10) * 1536);
        stepD(t + 3, lane, a2, W3,  xa, za, ldet); loadbuf(W3,  base + (size_t)(t + 11) * 1536);
        stepD(t + 4, lane, a2, W4,  xa, za, ldet); loadbuf(W4,  base + (size_t)(t + 12) * 1536);
        stepD(t + 5, lane, a2, W5,  xa, za, ldet); loadbuf(W5,  base + (size_t)(t + 13) * 1536);
        stepD(t + 6, lane, a2, W6,  xa, za, ldet); loadbuf(W6,  base + (size_t)(t + 14) * 1536);
        stepD(t + 7, lane, a2, W7,  xa, za, ldet); loadbuf(W7,  base + (size_t)(t + 15) * 1536);
    }
    // ---- second half: steps 64..119 with reloads (targets <= 127) ----
#pragma unroll 1
    for (int t = 0; t < 56; t += 8) {
        stepD(t + 0, lane, a2, W0,  xb, zb, ldet); loadbuf(W0,  base + (size_t)(t + 72) * 1536);
        stepD(t + 1, lane, a2, W1r, xb, zb, ldet); loadbuf(W1r, base + (size_t)(t + 73) * 1536);
        stepD(t + 2, lane, a2, W2r, xb, zb, ldet); loadbuf(W2r, base + (size_t)(t + 74) * 1536);
        stepD(t + 3, lane, a2, W3,  xb, zb, ldet); loadbuf(W3,  base + (size_t)(t + 75) * 1536);
        stepD(t + 4, lane, a2, W4,  xb, zb, ldet); loadbuf(W4,  base + (size_t)(t + 76) * 1536);
        stepD(t + 5, lane, a2, W5,  xb, zb, ldet); loadbuf(W5,  base + (size_t)(t + 77) * 1536);
        stepD(t + 6, lane, a2, W6,  xb, zb, ldet); loadbuf(W6,  base + (size_t)(t + 78) * 1536);
        stepD(t + 7, lane, a2, W7,  xb, zb, ldet); loadbuf(W7,  base + (size_t)(t + 79) * 1536);
    }
    // ---- peeled tail: steps 120..127, no reloads ----
    stepD(56, lane, a2, W0,  xb, zb, ldet);
    stepD(57, lane, a2, W1r, xb, zb, ldet);
    stepD(58, lane, a2, W2r, xb, zb, ldet);
    stepD(59, lane, a2, W3,  xb, zb, ldet);
    stepD(60, lane, a2, W4,  xb, zb, ldet);
    stepD(61, lane, a2, W5,  xb, zb, ldet);
    stepD(62, lane, a2, W6,  xb, zb, ldet);
    stepD(63, lane, a2, W7,  xb, zb, ldet);

    out[row * Dd + lane]      = za * Ea;       // un-fold E_d
    out[row * Dd + 64 + lane] = zb * Eb;
    float ldt = bcast_lane(ldet, 63);
    if (lane == 0) out[Bz * Dd + row] = LN2 * (ldt + Csum);
}

// ---------------- fallback (ws too small): masked direct loads ----------------
__global__ __launch_bounds__(64, 1) void iaf_fb_kernel(
    const float* __restrict__ x,  const float* __restrict__ W1,
    const float* __restrict__ b1, const float* __restrict__ W2,
    const float* __restrict__ b2, float* __restrict__ out)
{
    const int lane = (int)threadIdx.x;
    const int row  = (int)blockIdx.x;
    const int h0   = lane * 8;
    float a[8]; int mh[8];
#pragma unroll
    for (int k = 0; k < 8; ++k) { a[k] = b1[h0 + k]; mh[k] = ((h0 + k) % 127) + 1; }
    float xa  = x[row * Dd + lane], xb = x[row * Dd + 64 + lane];
    float b2a = b2[lane], b2b = b2[64 + lane], b2c = b2[128 + lane], b2d_ = b2[192 + lane];
    float za = 0.f, zb = 0.f, ld = 0.f;
    for (int d = 0; d < Dd; ++d) {
        float ps = 0.f, pm = 0.f;
#pragma unroll
        for (int k = 0; k < 8; ++k) {
            float h = fmaxf(a[k], 0.f);
            h = (mh[k] <= d) ? h : 0.f;
            ps = fmaf(h, W2[d * Hh + h0 + k], ps);
            pm = fmaf(h, W2[(Dd + d) * Hh + h0 + k], pm);
        }
        ps = wave_sum_bcast(ps);
        pm = wave_sum_bcast(pm);
        int dl = d & 63;
        float sd = ps + bcast_lane(d < 64 ? b2a : b2b, dl);
        float md = pm + bcast_lane(d < 64 ? b2c : b2d_, dl);
        float xv =      bcast_lane(d < 64 ? xa  : xb,  dl);
        float zd = (xv - md) * __expf(-sd);
        ld -= sd;
        if (dl == lane) { if (d < 64) za = zd; else zb = zd; }
#pragma unroll
        for (int k = 0; k < 8; ++k)
            if (d < mh[k]) a[k] = fmaf(zd, W1[(h0 + k) * Dd + d], a[k]);
    }
    out[row * Dd + lane]      = za;
    out[row * Dd + 64 + lane] = zb;
    if (lane == 0) out[Bz * Dd + row] = ld;
}

extern "C" void kernel_launch(void* const* d_in, const int* in_sizes, int n_in,
                              void* d_out, int out_size, void* d_ws, size_t ws_size,
                              hipStream_t stream) {
    const float* x  = (const float*)d_in[0];
    const float* W1 = (const float*)d_in[1];
    const float* b1 = (const float*)d_in[2];
    const float* W2 = (const float*)d_in[3];
    const float* b2 = (const float*)d_in[4];
    float* out = (float*)d_out;
    float* Wp  = (float*)d_ws;

    const size_t need = (size_t)Dd * 1536 * sizeof(float);  // 768 KB
    if (ws_size >= need) {
        pack_kernel<<<(Dd * Hh + 255) / 256, 256, 0, stream>>>(W1, W2, b2, Wp);
        iaf14_kernel<<<Bz, 64, 0, stream>>>(x, b1, b2, Wp, out);
    } else {
        iaf_fb_kernel<<<Bz, 64, 0, stream>>>(x, W1, b1, W2, b2, out);
    }
}